// Round 9
// baseline (140.855 us; speedup 1.0000x reference)
//
#include <hip/hip_runtime.h>
#include <stdint.h>

// SupConLossWithPrototype on MI355X.
// Only NOVEL columns of S=F F^T/T are ever used:
//   novel i: sumS = sum_{j novel, j!=i} S_ij, sumE = sum_{j novel, j!=i} exp(S_ij)
//   base  i: sumE over novel j only
// No compaction: Fz = novel ? bf16(5*log2e * f) : 0. MFMA D = Fb x Fz^T, then
// exp2(D) row-sums; base columns contribute exp2(0)=1, subtracted as (M-Nn).
// sum_j S_ij via linearity: dot(fb_i, g), g = colsum(Fz) (exact bf16 colsum).
//
// Round 9 k_main: rounds 5-8 proved (a) all staging variants identical
// (~43 us, stall-bound), (b) occupancy is REGISTER-capped (~11 waves/CU),
// not grid-capped (2x grid -> same occ, worse time). Remaining lever: ILP.
// Each wave now owns TWO independent 16-col slices per step (two separate
// load->MFMA->exp2 chains, shared accE row-sum accumulators) -> 2x
// independent work in flight per wave at the same wave count.

#define M_TOT 8192
#define K_DIM 128
#define B_PRO 100
#define INV_T 5.0f                          // 1/TEMP
#define C_SCALE 7.2134752044448170f         // 5 * log2(e)
#define INV_C   0.1386294361119891f         // ln2/5
#define CJ    1024                          // columns per k_main block
#define NCHUNK (M_TOT / CJ)                 // 8 column chunks
#define PS    136                           // k_proto2 proto LDS stride
#define FS    136                           // k_proto2 feat LDS stride

#if __has_builtin(__builtin_amdgcn_exp2f)
#define EXP2(x) __builtin_amdgcn_exp2f(x)
#else
#define EXP2(x) __expf((x) * 0.6931471805599453f)
#endif

typedef __attribute__((ext_vector_type(8))) short  short8;   // 8 bf16 (MFMA A/B frag)
typedef __attribute__((ext_vector_type(4))) float  floatx4;  // MFMA C/D frag

__device__ __forceinline__ float bf2f(unsigned short u) {
    union { unsigned int i; float f; } v; v.i = ((unsigned int)u) << 16; return v.f;
}
__device__ __forceinline__ unsigned short f2bf(float x) {   // RNE
    union { float f; unsigned int i; } v; v.f = x;
    return (unsigned short)((v.i + 0x7fffu + ((v.i >> 16) & 1u)) >> 16);
}
__device__ __forceinline__ float lo_bf(unsigned int u) {
    union { unsigned int i; float f; } v; v.i = u << 16; return v.f;
}
__device__ __forceinline__ float hi_bf(unsigned int u) {
    union { unsigned int i; float f; } v; v.i = u & 0xffff0000u; return v.f;
}

// ---------------------------------------------------------------- k_proto2
// 512 blocks x 256 thr; 16 feature rows per block. Emits Psum/expPsum/PLab/nf,
// Fb = bf16(f), Fz = novel? bf16(C*f):0, gpart[block] = block colsum(Fz),
// nfcnt[block] = block novel count. Block 0 zeroes out[0].
__global__ __launch_bounds__(256) void k_proto2(
        const float* __restrict__ feat, const int* __restrict__ labels,
        const float* __restrict__ protos, const int* __restrict__ plabels,
        float* __restrict__ Psum, float* __restrict__ expPsum,
        float* __restrict__ PLab, int* __restrict__ nf,
        int* __restrict__ nfcnt,
        unsigned short* __restrict__ Fb, unsigned short* __restrict__ Fz,
        float* __restrict__ gpart, float* __restrict__ out) {
    __shared__ unsigned short protoB[128 * PS];
    __shared__ unsigned short featB[16 * FS];
    __shared__ float zcol[16][128];
    __shared__ int labL[16];
    __shared__ int plabL[B_PRO];
    __shared__ int novL[16];

    const int tid = threadIdx.x;
    const int rowBase = blockIdx.x * 16;

    if (blockIdx.x == 0 && tid == 0) out[0] = 0.f;   // k_final accumulates later

    if (tid < B_PRO) plabL[tid] = plabels[tid];
    if (tid >= 128 && tid < 144) labL[tid - 128] = labels[rowBase + tid - 128];

    // stage protos -> bf16 LDS (rows >= 100 zeroed). thread: row tid>>1, half tid&1.
    {
        const int pr = tid >> 1, h = tid & 1;
        unsigned short* dst = &protoB[pr * PS + h * 64];
        if (pr < B_PRO) {
            const float* src = protos + pr * K_DIM + h * 64;
            #pragma unroll
            for (int j = 0; j < 16; ++j) {
                float4 v = ((const float4*)src)[j];
                *(ushort4*)&dst[j * 4] = make_ushort4(f2bf(v.x), f2bf(v.y), f2bf(v.z), f2bf(v.w));
            }
        } else {
            #pragma unroll
            for (int j = 0; j < 16; ++j) *(ushort4*)&dst[j * 4] = make_ushort4(0, 0, 0, 0);
        }
    }

    // stage this thread's feat segment (row rp, cols pq*8..+7) -> LDS + Fb.
    const int rp = tid >> 4, pq = tid & 15;
    float4 fa, fb4;
    {
        const float* src = feat + (size_t)(rowBase + rp) * K_DIM + pq * 8;
        fa  = ((const float4*)src)[0];
        fb4 = ((const float4*)src)[1];
        ushort4 o0 = make_ushort4(f2bf(fa.x), f2bf(fa.y), f2bf(fa.z), f2bf(fa.w));
        ushort4 o1 = make_ushort4(f2bf(fb4.x), f2bf(fb4.y), f2bf(fb4.z), f2bf(fb4.w));
        *(ushort4*)&featB[rp * FS + pq * 8]     = o0;
        *(ushort4*)&featB[rp * FS + pq * 8 + 4] = o1;
        unsigned short* fbd = Fb + (size_t)(rowBase + rp) * K_DIM + pq * 8;
        *(ushort4*)&fbd[0] = o0;
        *(ushort4*)&fbd[4] = o1;
    }
    __syncthreads();

    float acc[8];
    #pragma unroll
    for (int s = 0; s < 8; ++s) acc[s] = 0.f;

    const unsigned short* fRow = &featB[rp * FS];
    for (int kc = 0; kc < K_DIM; kc += 16) {
        uint4 q0 = *(const uint4*)&fRow[kc];
        uint4 q1 = *(const uint4*)&fRow[kc + 8];
        float f[16];
        f[0]=lo_bf(q0.x); f[1]=hi_bf(q0.x); f[2]=lo_bf(q0.y); f[3]=hi_bf(q0.y);
        f[4]=lo_bf(q0.z); f[5]=hi_bf(q0.z); f[6]=lo_bf(q0.w); f[7]=hi_bf(q0.w);
        f[8]=lo_bf(q1.x); f[9]=hi_bf(q1.x); f[10]=lo_bf(q1.y); f[11]=hi_bf(q1.y);
        f[12]=lo_bf(q1.z); f[13]=hi_bf(q1.z); f[14]=lo_bf(q1.w); f[15]=hi_bf(q1.w);
        #pragma unroll
        for (int s = 0; s < 8; ++s) {
            const int b = pq + (s & 3) * 16 + (s >> 2) * 64;
            const unsigned short* pRow = &protoB[b * PS];
            uint4 p0 = *(const uint4*)&pRow[kc];
            uint4 p1 = *(const uint4*)&pRow[kc + 8];
            float a = acc[s];
            a += lo_bf(p0.x)*f[0];  a += hi_bf(p0.x)*f[1];
            a += lo_bf(p0.y)*f[2];  a += hi_bf(p0.y)*f[3];
            a += lo_bf(p0.z)*f[4];  a += hi_bf(p0.z)*f[5];
            a += lo_bf(p0.w)*f[6];  a += hi_bf(p0.w)*f[7];
            a += lo_bf(p1.x)*f[8];  a += hi_bf(p1.x)*f[9];
            a += lo_bf(p1.y)*f[10]; a += hi_bf(p1.y)*f[11];
            a += lo_bf(p1.z)*f[12]; a += hi_bf(p1.z)*f[13];
            a += lo_bf(p1.w)*f[14]; a += hi_bf(p1.w)*f[15];
            acc[s] = a;
        }
    }

    // per-row epilogue: mask b<100, reduce over the 16 pq lanes
    const int lbl = labL[rp];
    float psum = 0.f, esum = 0.f, plab = 0.f, flg = 0.f;
    #pragma unroll
    for (int s = 0; s < 8; ++s) {
        const int b = pq + (s & 3) * 16 + (s >> 2) * 64;
        if (b < B_PRO) {
            const float Pv = acc[s] * INV_T;
            psum += Pv;
            esum += __expf(Pv);
            if (b == lbl) plab += Pv;
            if (plabL[b] == lbl) flg = 1.f;
        }
    }
    for (int off = 1; off < 16; off <<= 1) {
        psum += __shfl_xor(psum, off);
        esum += __shfl_xor(esum, off);
        plab += __shfl_xor(plab, off);
        flg  += __shfl_xor(flg,  off);
    }

    // Fz write + zcol (exact bf16 values into LDS for the column sum)
    {
        const bool nov = (flg == 0.f);
        ushort4 z0 = make_ushort4(0,0,0,0), z1 = z0;
        if (nov) {
            z0 = make_ushort4(f2bf(fa.x*C_SCALE), f2bf(fa.y*C_SCALE),
                              f2bf(fa.z*C_SCALE), f2bf(fa.w*C_SCALE));
            z1 = make_ushort4(f2bf(fb4.x*C_SCALE), f2bf(fb4.y*C_SCALE),
                              f2bf(fb4.z*C_SCALE), f2bf(fb4.w*C_SCALE));
        }
        unsigned short* fzd = Fz + (size_t)(rowBase + rp) * K_DIM + pq * 8;
        *(ushort4*)&fzd[0] = z0;
        *(ushort4*)&fzd[4] = z1;
        float* zc = &zcol[rp][pq * 8];
        zc[0] = bf2f(z0.x); zc[1] = bf2f(z0.y); zc[2] = bf2f(z0.z); zc[3] = bf2f(z0.w);
        zc[4] = bf2f(z1.x); zc[5] = bf2f(z1.y); zc[6] = bf2f(z1.z); zc[7] = bf2f(z1.w);
    }

    if (pq == 0) {
        const int i = rowBase + rp;
        Psum[i] = psum; expPsum[i] = esum; PLab[i] = plab;
        const int nov = (flg > 0.f) ? 0 : 1;
        nf[i] = nov;
        novL[rp] = nov;
    }

    __syncthreads();
    if (tid < 128) {
        float s = 0.f;
        #pragma unroll
        for (int r = 0; r < 16; ++r) s += zcol[r][tid];
        gpart[blockIdx.x * 128 + tid] = s;         // non-atomic partial
    } else if (tid == 255) {
        int c = 0;
        #pragma unroll
        for (int r = 0; r < 16; ++r) c += novL[r];
        nfcnt[blockIdx.x] = c;                     // non-atomic partial
    }
}

// ---------------------------------------------------------------- k_main
// Block = 256 thr (4 waves), 64 rows x CJ cols of exp2(D) row-sums.
// a_frag loaded once from global (AGPR/register resident). Each wave owns
// TWO independent 16-col slices per 128-col step (chains A/B), streamed
// straight from L2 as b128 gathers. No LDS tiles, no barriers. The two
// chains give 2x independent latency-covering work per wave.
__global__ __launch_bounds__(256) void k_main(const unsigned short* __restrict__ Fb,
                                              const unsigned short* __restrict__ Fz,
                                              float* __restrict__ rowSumPart) {
    __shared__ float Re[4][64];

    const int rowBase = blockIdx.y * 64;
    const int tid = threadIdx.x;
    const int wave = tid >> 6, lane = tid & 63;
    const int quad = lane >> 4, c = lane & 15;

    // A fragments straight from global: rows mt*16+c, k = ks*32+quad*8..+7
    short8 a_frag[4][4];
    #pragma unroll
    for (int mt = 0; mt < 4; ++mt)
        #pragma unroll
        for (int ks = 0; ks < 4; ++ks)
            a_frag[mt][ks] = *(const short8*)(Fb + (size_t)(rowBase + mt * 16 + c) * K_DIM
                                              + ks * 32 + quad * 8);

    float accE[4][4];
    #pragma unroll
    for (int mt = 0; mt < 4; ++mt)
        #pragma unroll
        for (int r = 0; r < 4; ++r) accE[mt][r] = 0.f;

    // chain A col: colBase + s*128 + wave*16 + c ; chain B col: + 64
    const unsigned short* pA = Fz + (size_t)(blockIdx.x * CJ + wave * 16 + c) * K_DIM
                               + quad * 8;
    const unsigned short* pB = pA + (size_t)64 * K_DIM;
    const size_t stepStride = (size_t)128 * K_DIM;

    #pragma unroll 1
    for (int s = 0; s < CJ / 128; ++s) {
        const short8 a0 = *(const short8*)(pA);
        const short8 a1 = *(const short8*)(pA + 32);
        const short8 a2 = *(const short8*)(pA + 64);
        const short8 a3 = *(const short8*)(pA + 96);
        const short8 b0 = *(const short8*)(pB);
        const short8 b1 = *(const short8*)(pB + 32);
        const short8 b2 = *(const short8*)(pB + 64);
        const short8 b3 = *(const short8*)(pB + 96);
        pA += stepStride; pB += stepStride;

        floatx4 DA[4], DB[4];
        #pragma unroll
        for (int mt = 0; mt < 4; ++mt) {
            DA[mt] = (floatx4){0.f, 0.f, 0.f, 0.f};
            DB[mt] = (floatx4){0.f, 0.f, 0.f, 0.f};
        }
        #pragma unroll
        for (int mt = 0; mt < 4; ++mt) {
            DA[mt] = __builtin_amdgcn_mfma_f32_16x16x32_bf16(a_frag[mt][0], a0, DA[mt], 0, 0, 0);
            DB[mt] = __builtin_amdgcn_mfma_f32_16x16x32_bf16(a_frag[mt][0], b0, DB[mt], 0, 0, 0);
            DA[mt] = __builtin_amdgcn_mfma_f32_16x16x32_bf16(a_frag[mt][1], a1, DA[mt], 0, 0, 0);
            DB[mt] = __builtin_amdgcn_mfma_f32_16x16x32_bf16(a_frag[mt][1], b1, DB[mt], 0, 0, 0);
            DA[mt] = __builtin_amdgcn_mfma_f32_16x16x32_bf16(a_frag[mt][2], a2, DA[mt], 0, 0, 0);
            DB[mt] = __builtin_amdgcn_mfma_f32_16x16x32_bf16(a_frag[mt][2], b2, DB[mt], 0, 0, 0);
            DA[mt] = __builtin_amdgcn_mfma_f32_16x16x32_bf16(a_frag[mt][3], a3, DA[mt], 0, 0, 0);
            DB[mt] = __builtin_amdgcn_mfma_f32_16x16x32_bf16(a_frag[mt][3], b3, DB[mt], 0, 0, 0);
        }
        #pragma unroll
        for (int mt = 0; mt < 4; ++mt)
            #pragma unroll
            for (int r = 0; r < 4; ++r) {
                accE[mt][r] += EXP2(DA[mt][r]);   // base cols: exp2(0)=1, removed later
                accE[mt][r] += EXP2(DB[mt][r]);
            }
    }

    // reduce over the 16-lane column group
    #pragma unroll
    for (int mt = 0; mt < 4; ++mt)
        #pragma unroll
        for (int r = 0; r < 4; ++r) {
            float e = accE[mt][r];
            for (int off = 1; off < 16; off <<= 1) e += __shfl_xor(e, off);
            if (c == 0) Re[wave][mt * 16 + quad * 4 + r] = e;
        }
    __syncthreads();
    if (tid < 64) {
        const float e = Re[0][tid] + Re[1][tid] + Re[2][tid] + Re[3][tid];
        rowSumPart[(size_t)blockIdx.x * M_TOT + rowBase + tid] = e;   // block-unique
    }
}

// ---------------------------------------------------------------- k_final
// 512 blocks x 256 thr, 16 rows/block. Preamble: g[128] = sum of 512 gpart
// rows; Nn = sum of nfcnt. Per row i: sZ = dot(Fb_i, g), dd = dot(Fb_i,Fz_i)
// = D_ii; sumE = sum over the NCHUNK rowSumPart partials (lane-parallel).
__global__ __launch_bounds__(256) void k_final(
        const int* __restrict__ nf,
        const float* __restrict__ rowSumPart,
        const float* __restrict__ Psum, const float* __restrict__ expPsum,
        const float* __restrict__ PLab,
        const unsigned short* __restrict__ Fb, const unsigned short* __restrict__ Fz,
        const float* __restrict__ gpart, const int* __restrict__ nfcnt,
        float* __restrict__ out) {
    __shared__ float g[128];
    __shared__ float gtmp[128];
    __shared__ float sh[16];
    __shared__ int shNn;
    const int tid = threadIdx.x;

    // g: two half-sums over the 512 gpart rows
    {
        const int col = tid & 127, h = tid >> 7;
        float s = 0.f;
        #pragma unroll 8
        for (int r = h * 256; r < h * 256 + 256; ++r) s += gpart[r * 128 + col];
        if (h) gtmp[col] = s; else g[col] = s;
    }
    // Nn: wave 0 reduces nfcnt[512]
    if (tid < 64) {
        int cs = 0;
        #pragma unroll
        for (int r = 0; r < 8; ++r) cs += nfcnt[tid + 64 * r];
        for (int off = 1; off < 64; off <<= 1) cs += __shfl_xor(cs, off);
        if (tid == 0) shNn = cs;
    }
    __syncthreads();
    if (tid < 128) g[tid] += gtmp[tid];
    __syncthreads();

    const int rp = tid >> 4, u = tid & 15;
    const int i = blockIdx.x * 16 + rp;
    uint4 qb = ((const uint4*)Fb)[(size_t)i * 16 + u];
    uint4 qz = ((const uint4*)Fz)[(size_t)i * 16 + u];
    float sZ = 0.f, dd = 0.f;
    {
        const float* gv = &g[u * 8];
        float fb[8], fz[8];
        fb[0]=lo_bf(qb.x); fb[1]=hi_bf(qb.x); fb[2]=lo_bf(qb.y); fb[3]=hi_bf(qb.y);
        fb[4]=lo_bf(qb.z); fb[5]=hi_bf(qb.z); fb[6]=lo_bf(qb.w); fb[7]=hi_bf(qb.w);
        fz[0]=lo_bf(qz.x); fz[1]=hi_bf(qz.x); fz[2]=lo_bf(qz.y); fz[3]=hi_bf(qz.y);
        fz[4]=lo_bf(qz.z); fz[5]=hi_bf(qz.z); fz[6]=lo_bf(qz.w); fz[7]=hi_bf(qz.w);
        #pragma unroll
        for (int e = 0; e < 8; ++e) { sZ += fb[e] * gv[e]; dd += fb[e] * fz[e]; }
    }
    // rowSumExp partials: lanes u < NCHUNK each grab one chunk's partial
    float ep = (u < NCHUNK) ? rowSumPart[(size_t)u * M_TOT + i] : 0.f;
    for (int off = 1; off < 16; off <<= 1) {
        sZ += __shfl_xor(sZ, off);
        dd += __shfl_xor(dd, off);
        ep += __shfl_xor(ep, off);
    }

    if (u == 0) {
        const int Nn = shNn;
        const float nzero = (float)(M_TOT - Nn);
        const float sumEadj = ep - nzero;             // remove base-column exp2(0)=1 terms
        float contrib;
        if (nf[i]) {
            const float cnt = (float)(Nn - 1);
            const float sumE = sumEadj - EXP2(dd);            // remove own diagonal
            const float denom = sumE + Psum[i];               // + RAW proto logit sum (faithful)
            const float sumS_raw = (sZ - dd) * INV_C;         // sum_{j novel, j!=i} dot_ij
            const float num = INV_T * sumS_raw - logf(denom) * cnt;
            const float sc = cnt > 0.f ? cnt : 1.f;
            contrib = -(num / sc);
        } else {
            contrib = -(PLab[i] - logf(sumEadj + expPsum[i]));
        }
        sh[rp] = contrib;
    }
    __syncthreads();
    if (tid == 0) {
        float s = 0.f;
        #pragma unroll
        for (int r = 0; r < 16; ++r) s += sh[r];
        atomicAdd(out, s * (1.0f / (float)M_TOT));
    }
}

// ---------------------------------------------------------------- launch
extern "C" void kernel_launch(void* const* d_in, const int* in_sizes, int n_in,
                              void* d_out, int out_size, void* d_ws, size_t ws_size,
                              hipStream_t stream) {
    const float* feat    = (const float*)d_in[0];
    const int*   labels  = (const int*)d_in[1];
    const float* protos  = (const float*)d_in[2];
    const int*   plabels = (const int*)d_in[3];
    float* out = (float*)d_out;

    char* ws = (char*)d_ws;
    int*   nfcnt      = (int*)ws;                    // 512 ints
    float* gpart      = (float*)(ws + 4096);         // 512 x 128 fp32 (256 KB)
    float* rowSumPart = (float*)(ws + 266240);       // NCHUNK x 8192 fp32 (256 KB)
    float* Psum       = (float*)(ws + 528384);
    float* expPsum    = (float*)(ws + 561152);
    float* PLab       = (float*)(ws + 593920);
    int*   nf         = (int*)(ws + 626688);
    unsigned short* Fb = (unsigned short*)(ws + 659456);            // 2 MB, 16B aligned
    unsigned short* Fz = (unsigned short*)(ws + 659456 + 2097152);  // 2 MB, 16B aligned

    k_proto2<<<M_TOT / 16, 256, 0, stream>>>(feat, labels, protos, plabels,
                                             Psum, expPsum, PLab, nf, nfcnt,
                                             Fb, Fz, gpart, out);
    dim3 gmain(NCHUNK, M_TOT / 64);   // 8 x 128; blockIdx.x == XCD -> L2-partitioned Fz
    k_main<<<gmain, 256, 0, stream>>>(Fb, Fz, rowSumPart);
    k_final<<<M_TOT / 16, 256, 0, stream>>>(nf, rowSumPart, Psum, expPsum, PLab,
                                            Fb, Fz, gpart, nfcnt, out);
}

// Round 10
// 138.397 us; speedup vs baseline: 1.0178x; 1.0178x over previous
//
#include <hip/hip_runtime.h>
#include <stdint.h>

// SupConLossWithPrototype on MI355X.
// Only NOVEL columns of S=F F^T/T are ever used:
//   novel i: sumS = sum_{j novel, j!=i} S_ij, sumE = sum_{j novel, j!=i} exp(S_ij)
//   base  i: sumE over novel j only
// No compaction: Fz = novel ? bf16(5*log2e * f) : 0. MFMA D = Fb x Fz^T, then
// exp2(D) row-sums; base columns contribute exp2(0)=1, subtracted as (M-Nn).
// sum_j S_ij via linearity: dot(fb_i, g), g = colsum(Fz) (exact bf16 colsum).
//
// Round 10: rounds 5-9 isolated the real wall — per-CU VMEM-path BYTES
// (~10 B/cyc/CU): 284 MB of per-wave-private column reads = 1.1 MB/CU
// = the invariant ~43 us, regardless of staging/ILP/TLP. Fix the DATAFLOW:
// 256-row x 512-col block tiles; the 64-col B tile is staged once per block
// in LDS and shared by 4 waves (LDS bypasses the VMEM path); each wave owns
// a private 64-row a_frag set. Volume: 8192^2*256*(1/256+1/512) = 96 MB (3x).

#define M_TOT 8192
#define K_DIM 128
#define B_PRO 100
#define INV_T 5.0f                          // 1/TEMP
#define C_SCALE 7.2134752044448170f         // 5 * log2(e)
#define INV_C   0.1386294361119891f         // ln2/5
#define CJ     512                          // columns per k_main block
#define ROWS_B 256                          // rows per k_main block (4 waves x 64)
#define NCHUNK (M_TOT / CJ)                 // 16 column chunks
#define LDB    136                          // B-tile LDS stride (128+8 pad -> 2-way only)
#define PS     136                          // k_proto2 proto LDS stride
#define FS     136                          // k_proto2 feat LDS stride

#if __has_builtin(__builtin_amdgcn_exp2f)
#define EXP2(x) __builtin_amdgcn_exp2f(x)
#else
#define EXP2(x) __expf((x) * 0.6931471805599453f)
#endif

typedef __attribute__((ext_vector_type(8))) short  short8;   // 8 bf16 (MFMA A/B frag)
typedef __attribute__((ext_vector_type(4))) float  floatx4;  // MFMA C/D frag

__device__ __forceinline__ float bf2f(unsigned short u) {
    union { unsigned int i; float f; } v; v.i = ((unsigned int)u) << 16; return v.f;
}
__device__ __forceinline__ unsigned short f2bf(float x) {   // RNE
    union { float f; unsigned int i; } v; v.f = x;
    return (unsigned short)((v.i + 0x7fffu + ((v.i >> 16) & 1u)) >> 16);
}
__device__ __forceinline__ float lo_bf(unsigned int u) {
    union { unsigned int i; float f; } v; v.i = u << 16; return v.f;
}
__device__ __forceinline__ float hi_bf(unsigned int u) {
    union { unsigned int i; float f; } v; v.i = u & 0xffff0000u; return v.f;
}

// ---------------------------------------------------------------- k_proto2
// 512 blocks x 256 thr; 16 feature rows per block. Emits Psum/expPsum/PLab/nf,
// Fb = bf16(f), Fz = novel? bf16(C*f):0, gpart[block] = block colsum(Fz),
// nfcnt[block] = block novel count. Block 0 zeroes out[0].
__global__ __launch_bounds__(256) void k_proto2(
        const float* __restrict__ feat, const int* __restrict__ labels,
        const float* __restrict__ protos, const int* __restrict__ plabels,
        float* __restrict__ Psum, float* __restrict__ expPsum,
        float* __restrict__ PLab, int* __restrict__ nf,
        int* __restrict__ nfcnt,
        unsigned short* __restrict__ Fb, unsigned short* __restrict__ Fz,
        float* __restrict__ gpart, float* __restrict__ out) {
    __shared__ unsigned short protoB[128 * PS];
    __shared__ unsigned short featB[16 * FS];
    __shared__ float zcol[16][128];
    __shared__ int labL[16];
    __shared__ int plabL[B_PRO];
    __shared__ int novL[16];

    const int tid = threadIdx.x;
    const int rowBase = blockIdx.x * 16;

    if (blockIdx.x == 0 && tid == 0) out[0] = 0.f;   // k_final accumulates later

    if (tid < B_PRO) plabL[tid] = plabels[tid];
    if (tid >= 128 && tid < 144) labL[tid - 128] = labels[rowBase + tid - 128];

    // stage protos -> bf16 LDS (rows >= 100 zeroed). thread: row tid>>1, half tid&1.
    {
        const int pr = tid >> 1, h = tid & 1;
        unsigned short* dst = &protoB[pr * PS + h * 64];
        if (pr < B_PRO) {
            const float* src = protos + pr * K_DIM + h * 64;
            #pragma unroll
            for (int j = 0; j < 16; ++j) {
                float4 v = ((const float4*)src)[j];
                *(ushort4*)&dst[j * 4] = make_ushort4(f2bf(v.x), f2bf(v.y), f2bf(v.z), f2bf(v.w));
            }
        } else {
            #pragma unroll
            for (int j = 0; j < 16; ++j) *(ushort4*)&dst[j * 4] = make_ushort4(0, 0, 0, 0);
        }
    }

    // stage this thread's feat segment (row rp, cols pq*8..+7) -> LDS + Fb.
    const int rp = tid >> 4, pq = tid & 15;
    float4 fa, fb4;
    {
        const float* src = feat + (size_t)(rowBase + rp) * K_DIM + pq * 8;
        fa  = ((const float4*)src)[0];
        fb4 = ((const float4*)src)[1];
        ushort4 o0 = make_ushort4(f2bf(fa.x), f2bf(fa.y), f2bf(fa.z), f2bf(fa.w));
        ushort4 o1 = make_ushort4(f2bf(fb4.x), f2bf(fb4.y), f2bf(fb4.z), f2bf(fb4.w));
        *(ushort4*)&featB[rp * FS + pq * 8]     = o0;
        *(ushort4*)&featB[rp * FS + pq * 8 + 4] = o1;
        unsigned short* fbd = Fb + (size_t)(rowBase + rp) * K_DIM + pq * 8;
        *(ushort4*)&fbd[0] = o0;
        *(ushort4*)&fbd[4] = o1;
    }
    __syncthreads();

    float acc[8];
    #pragma unroll
    for (int s = 0; s < 8; ++s) acc[s] = 0.f;

    const unsigned short* fRow = &featB[rp * FS];
    for (int kc = 0; kc < K_DIM; kc += 16) {
        uint4 q0 = *(const uint4*)&fRow[kc];
        uint4 q1 = *(const uint4*)&fRow[kc + 8];
        float f[16];
        f[0]=lo_bf(q0.x); f[1]=hi_bf(q0.x); f[2]=lo_bf(q0.y); f[3]=hi_bf(q0.y);
        f[4]=lo_bf(q0.z); f[5]=hi_bf(q0.z); f[6]=lo_bf(q0.w); f[7]=hi_bf(q0.w);
        f[8]=lo_bf(q1.x); f[9]=hi_bf(q1.x); f[10]=lo_bf(q1.y); f[11]=hi_bf(q1.y);
        f[12]=lo_bf(q1.z); f[13]=hi_bf(q1.z); f[14]=lo_bf(q1.w); f[15]=hi_bf(q1.w);
        #pragma unroll
        for (int s = 0; s < 8; ++s) {
            const int b = pq + (s & 3) * 16 + (s >> 2) * 64;
            const unsigned short* pRow = &protoB[b * PS];
            uint4 p0 = *(const uint4*)&pRow[kc];
            uint4 p1 = *(const uint4*)&pRow[kc + 8];
            float a = acc[s];
            a += lo_bf(p0.x)*f[0];  a += hi_bf(p0.x)*f[1];
            a += lo_bf(p0.y)*f[2];  a += hi_bf(p0.y)*f[3];
            a += lo_bf(p0.z)*f[4];  a += hi_bf(p0.z)*f[5];
            a += lo_bf(p0.w)*f[6];  a += hi_bf(p0.w)*f[7];
            a += lo_bf(p1.x)*f[8];  a += hi_bf(p1.x)*f[9];
            a += lo_bf(p1.y)*f[10]; a += hi_bf(p1.y)*f[11];
            a += lo_bf(p1.z)*f[12]; a += hi_bf(p1.z)*f[13];
            a += lo_bf(p1.w)*f[14]; a += hi_bf(p1.w)*f[15];
            acc[s] = a;
        }
    }

    // per-row epilogue: mask b<100, reduce over the 16 pq lanes
    const int lbl = labL[rp];
    float psum = 0.f, esum = 0.f, plab = 0.f, flg = 0.f;
    #pragma unroll
    for (int s = 0; s < 8; ++s) {
        const int b = pq + (s & 3) * 16 + (s >> 2) * 64;
        if (b < B_PRO) {
            const float Pv = acc[s] * INV_T;
            psum += Pv;
            esum += __expf(Pv);
            if (b == lbl) plab += Pv;
            if (plabL[b] == lbl) flg = 1.f;
        }
    }
    for (int off = 1; off < 16; off <<= 1) {
        psum += __shfl_xor(psum, off);
        esum += __shfl_xor(esum, off);
        plab += __shfl_xor(plab, off);
        flg  += __shfl_xor(flg,  off);
    }

    // Fz write + zcol (exact bf16 values into LDS for the column sum)
    {
        const bool nov = (flg == 0.f);
        ushort4 z0 = make_ushort4(0,0,0,0), z1 = z0;
        if (nov) {
            z0 = make_ushort4(f2bf(fa.x*C_SCALE), f2bf(fa.y*C_SCALE),
                              f2bf(fa.z*C_SCALE), f2bf(fa.w*C_SCALE));
            z1 = make_ushort4(f2bf(fb4.x*C_SCALE), f2bf(fb4.y*C_SCALE),
                              f2bf(fb4.z*C_SCALE), f2bf(fb4.w*C_SCALE));
        }
        unsigned short* fzd = Fz + (size_t)(rowBase + rp) * K_DIM + pq * 8;
        *(ushort4*)&fzd[0] = z0;
        *(ushort4*)&fzd[4] = z1;
        float* zc = &zcol[rp][pq * 8];
        zc[0] = bf2f(z0.x); zc[1] = bf2f(z0.y); zc[2] = bf2f(z0.z); zc[3] = bf2f(z0.w);
        zc[4] = bf2f(z1.x); zc[5] = bf2f(z1.y); zc[6] = bf2f(z1.z); zc[7] = bf2f(z1.w);
    }

    if (pq == 0) {
        const int i = rowBase + rp;
        Psum[i] = psum; expPsum[i] = esum; PLab[i] = plab;
        const int nov = (flg > 0.f) ? 0 : 1;
        nf[i] = nov;
        novL[rp] = nov;
    }

    __syncthreads();
    if (tid < 128) {
        float s = 0.f;
        #pragma unroll
        for (int r = 0; r < 16; ++r) s += zcol[r][tid];
        gpart[blockIdx.x * 128 + tid] = s;         // non-atomic partial
    } else if (tid == 255) {
        int c = 0;
        #pragma unroll
        for (int r = 0; r < 16; ++r) c += novL[r];
        nfcnt[blockIdx.x] = c;                     // non-atomic partial
    }
}

// ---------------------------------------------------------------- k_main
// Block = 256 thr (4 waves). Tile: 256 rows (wave w owns rows w*64..+64,
// a_frag register-resident) x CJ cols. Per 64-col step: the block stages a
// 16 KB B tile into LDS (coalesced, stride-136 padded), ALL 4 waves consume
// it (4 sub-tiles x 16 MFMA + 16 exp2). LDS reads bypass the per-CU VMEM
// byte wall; global volume drops 284 -> 96 MB. Simple 2-barrier staging
// (rounds 5-9: mechanism doesn't matter, bytes do). Waves own disjoint rows
// -> no cross-wave epilogue reduce.
__global__ __launch_bounds__(256) void k_main(const unsigned short* __restrict__ Fb,
                                              const unsigned short* __restrict__ Fz,
                                              float* __restrict__ rowSumPart) {
    __shared__ __align__(16) unsigned short Bl[2][64 * LDB];

    const int colBase = blockIdx.x * CJ;
    const int rowBase = blockIdx.y * ROWS_B;
    const int tid = threadIdx.x;
    const int wave = tid >> 6, lane = tid & 63;
    const int quad = lane >> 4, c = lane & 15;

    // wave-private A fragments: rows rowBase + wave*64 + mt*16 + c
    short8 a_frag[4][4];
    #pragma unroll
    for (int mt = 0; mt < 4; ++mt)
        #pragma unroll
        for (int ks = 0; ks < 4; ++ks)
            a_frag[mt][ks] = *(const short8*)(Fb
                + (size_t)(rowBase + wave * 64 + mt * 16 + c) * K_DIM + ks * 32 + quad * 8);

    float accE[4][4];
    #pragma unroll
    for (int mt = 0; mt < 4; ++mt)
        #pragma unroll
        for (int r = 0; r < 4; ++r) accE[mt][r] = 0.f;

    // staging map: thread handles 8-short chunks f = tid + q*256;
    // cc = f>>4 (tile col 0..63), off = (f&15)*8; LDS addr cc*LDB + off.
    const int NSTEP = CJ / 64;
    #pragma unroll 1
    for (int js = 0; js < NSTEP; ++js) {
        const int buf = js & 1;
        uint4 st[4];
        #pragma unroll
        for (int q = 0; q < 4; ++q) {
            const int f = tid + q * 256, cc = f >> 4, off = (f & 15) * 8;
            st[q] = *(const uint4*)(Fz + (size_t)(colBase + js * 64 + cc) * K_DIM + off);
        }
        __syncthreads();   // all waves done reading this buffer (previous use)
        #pragma unroll
        for (int q = 0; q < 4; ++q) {
            const int f = tid + q * 256, cc = f >> 4, off = (f & 15) * 8;
            *(uint4*)&Bl[buf][cc * LDB + off] = st[q];
        }
        __syncthreads();   // tile visible to all waves

        #pragma unroll
        for (int sub = 0; sub < 4; ++sub) {
            const unsigned short* bb = &Bl[buf][(sub * 16 + c) * LDB + quad * 8];
            const short8 b0 = *(const short8*)(bb);
            const short8 b1 = *(const short8*)(bb + 32);
            const short8 b2 = *(const short8*)(bb + 64);
            const short8 b3 = *(const short8*)(bb + 96);

            floatx4 D[4];
            #pragma unroll
            for (int mt = 0; mt < 4; ++mt) D[mt] = (floatx4){0.f, 0.f, 0.f, 0.f};
            #pragma unroll
            for (int mt = 0; mt < 4; ++mt) {
                D[mt] = __builtin_amdgcn_mfma_f32_16x16x32_bf16(a_frag[mt][0], b0, D[mt], 0, 0, 0);
                D[mt] = __builtin_amdgcn_mfma_f32_16x16x32_bf16(a_frag[mt][1], b1, D[mt], 0, 0, 0);
                D[mt] = __builtin_amdgcn_mfma_f32_16x16x32_bf16(a_frag[mt][2], b2, D[mt], 0, 0, 0);
                D[mt] = __builtin_amdgcn_mfma_f32_16x16x32_bf16(a_frag[mt][3], b3, D[mt], 0, 0, 0);
            }
            #pragma unroll
            for (int mt = 0; mt < 4; ++mt)
                #pragma unroll
                for (int r = 0; r < 4; ++r)
                    accE[mt][r] += EXP2(D[mt][r]);   // base cols: exp2(0)=1, removed later
        }
    }

    // per-wave epilogue (disjoint rows): butterfly over the 16-lane col group
    #pragma unroll
    for (int mt = 0; mt < 4; ++mt)
        #pragma unroll
        for (int r = 0; r < 4; ++r) {
            float e = accE[mt][r];
            for (int off = 1; off < 16; off <<= 1) e += __shfl_xor(e, off);
            if (c == 0) {
                const int row = rowBase + wave * 64 + mt * 16 + quad * 4 + r;
                rowSumPart[(size_t)blockIdx.x * M_TOT + row] = e;   // block-unique
            }
        }
}

// ---------------------------------------------------------------- k_final
// 512 blocks x 256 thr, 16 rows/block. Preamble: g[128] = sum of 512 gpart
// rows; Nn = sum of nfcnt. Per row i: sZ = dot(Fb_i, g), dd = dot(Fb_i,Fz_i)
// = D_ii; sumE = sum over the NCHUNK=16 rowSumPart partials (lane-parallel).
__global__ __launch_bounds__(256) void k_final(
        const int* __restrict__ nf,
        const float* __restrict__ rowSumPart,
        const float* __restrict__ Psum, const float* __restrict__ expPsum,
        const float* __restrict__ PLab,
        const unsigned short* __restrict__ Fb, const unsigned short* __restrict__ Fz,
        const float* __restrict__ gpart, const int* __restrict__ nfcnt,
        float* __restrict__ out) {
    __shared__ float g[128];
    __shared__ float gtmp[128];
    __shared__ float sh[16];
    __shared__ int shNn;
    const int tid = threadIdx.x;

    // g: two half-sums over the 512 gpart rows
    {
        const int col = tid & 127, h = tid >> 7;
        float s = 0.f;
        #pragma unroll 8
        for (int r = h * 256; r < h * 256 + 256; ++r) s += gpart[r * 128 + col];
        if (h) gtmp[col] = s; else g[col] = s;
    }
    // Nn: wave 0 reduces nfcnt[512]
    if (tid < 64) {
        int cs = 0;
        #pragma unroll
        for (int r = 0; r < 8; ++r) cs += nfcnt[tid + 64 * r];
        for (int off = 1; off < 64; off <<= 1) cs += __shfl_xor(cs, off);
        if (tid == 0) shNn = cs;
    }
    __syncthreads();
    if (tid < 128) g[tid] += gtmp[tid];
    __syncthreads();

    const int rp = tid >> 4, u = tid & 15;
    const int i = blockIdx.x * 16 + rp;
    uint4 qb = ((const uint4*)Fb)[(size_t)i * 16 + u];
    uint4 qz = ((const uint4*)Fz)[(size_t)i * 16 + u];
    float sZ = 0.f, dd = 0.f;
    {
        const float* gv = &g[u * 8];
        float fb[8], fz[8];
        fb[0]=lo_bf(qb.x); fb[1]=hi_bf(qb.x); fb[2]=lo_bf(qb.y); fb[3]=hi_bf(qb.y);
        fb[4]=lo_bf(qb.z); fb[5]=hi_bf(qb.z); fb[6]=lo_bf(qb.w); fb[7]=hi_bf(qb.w);
        fz[0]=lo_bf(qz.x); fz[1]=hi_bf(qz.x); fz[2]=lo_bf(qz.y); fz[3]=hi_bf(qz.y);
        fz[4]=lo_bf(qz.z); fz[5]=hi_bf(qz.z); fz[6]=lo_bf(qz.w); fz[7]=hi_bf(qz.w);
        #pragma unroll
        for (int e = 0; e < 8; ++e) { sZ += fb[e] * gv[e]; dd += fb[e] * fz[e]; }
    }
    // rowSumExp partials: all 16 lanes grab one chunk's partial (NCHUNK=16)
    float ep = rowSumPart[(size_t)u * M_TOT + i];
    for (int off = 1; off < 16; off <<= 1) {
        sZ += __shfl_xor(sZ, off);
        dd += __shfl_xor(dd, off);
        ep += __shfl_xor(ep, off);
    }

    if (u == 0) {
        const int Nn = shNn;
        const float nzero = (float)(M_TOT - Nn);
        const float sumEadj = ep - nzero;             // remove base-column exp2(0)=1 terms
        float contrib;
        if (nf[i]) {
            const float cnt = (float)(Nn - 1);
            const float sumE = sumEadj - EXP2(dd);            // remove own diagonal
            const float denom = sumE + Psum[i];               // + RAW proto logit sum (faithful)
            const float sumS_raw = (sZ - dd) * INV_C;         // sum_{j novel, j!=i} dot_ij
            const float num = INV_T * sumS_raw - logf(denom) * cnt;
            const float sc = cnt > 0.f ? cnt : 1.f;
            contrib = -(num / sc);
        } else {
            contrib = -(PLab[i] - logf(sumEadj + expPsum[i]));
        }
        sh[rp] = contrib;
    }
    __syncthreads();
    if (tid == 0) {
        float s = 0.f;
        #pragma unroll
        for (int r = 0; r < 16; ++r) s += sh[r];
        atomicAdd(out, s * (1.0f / (float)M_TOT));
    }
}

// ---------------------------------------------------------------- launch
extern "C" void kernel_launch(void* const* d_in, const int* in_sizes, int n_in,
                              void* d_out, int out_size, void* d_ws, size_t ws_size,
                              hipStream_t stream) {
    const float* feat    = (const float*)d_in[0];
    const int*   labels  = (const int*)d_in[1];
    const float* protos  = (const float*)d_in[2];
    const int*   plabels = (const int*)d_in[3];
    float* out = (float*)d_out;

    char* ws = (char*)d_ws;
    int*   nfcnt      = (int*)ws;                    // 512 ints
    float* gpart      = (float*)(ws + 4096);         // 512 x 128 fp32 (256 KB)
    float* rowSumPart = (float*)(ws + 266240);       // NCHUNK=16 x 8192 fp32 (512 KB)
    float* Psum       = (float*)(ws + 790528);
    float* expPsum    = (float*)(ws + 823296);
    float* PLab       = (float*)(ws + 856064);
    int*   nf         = (int*)(ws + 888832);
    unsigned short* Fb = (unsigned short*)(ws + 921600);            // 2 MB, 16B aligned
    unsigned short* Fz = (unsigned short*)(ws + 921600 + 2097152);  // 2 MB, 16B aligned

    k_proto2<<<M_TOT / 16, 256, 0, stream>>>(feat, labels, protos, plabels,
                                             Psum, expPsum, PLab, nf, nfcnt,
                                             Fb, Fz, gpart, out);
    dim3 gmain(NCHUNK, M_TOT / ROWS_B);   // 16 x 32 = 512 blocks, 2/CU
    k_main<<<gmain, 256, 0, stream>>>(Fb, Fz, rowSumPart);
    k_final<<<M_TOT / 16, 256, 0, stream>>>(nf, rowSumPart, Psum, expPsum, PLab,
                                            Fb, Fz, gpart, nfcnt, out);
}

// Round 11
// 124.851 us; speedup vs baseline: 1.1282x; 1.1085x over previous
//
#include <hip/hip_runtime.h>
#include <stdint.h>

// SupConLossWithPrototype on MI355X.
// Only NOVEL columns of S=F F^T/T are ever used:
//   novel i: sumS = sum_{j novel, j!=i} S_ij, sumE = sum_{j novel, j!=i} exp(S_ij)
//   base  i: sumE over novel j only
// No compaction: Fz = novel ? bf16(5*log2e * f) : 0. MFMA D = Fb x Fz^T, then
// exp2(D) row-sums; base columns contribute exp2(0)=1, subtracted as (M-Nn).
// sum_j S_ij via linearity: dot(fb_i, g), g = colsum(Fz) (exact bf16 colsum).
//
// Round 11: k_main reverted to the round-6 body (measured best of 6 variants:
// direct/reg-prefetch/async-DMA/2xTLP/2xILP/LDS-shared all 43-53 us — hard
// plateau, all pipes <16%). New: k_main blocks with y==0 reduce gpart->g and
// nfcnt->Nn ONCE (hidden under the other blocks); k_final's preamble becomes
// a trivial load, deleting 512x-redundant 256 KB reduces (~134 MB L2).

#define M_TOT 8192
#define K_DIM 128
#define B_PRO 100
#define INV_T 5.0f                          // 1/TEMP
#define C_SCALE 7.2134752044448170f         // 5 * log2(e)
#define INV_C   0.1386294361119891f         // ln2/5
#define CJ    1024                          // columns per k_main block
#define NCHUNK (M_TOT / CJ)                 // 8 column chunks
#define PS    136                           // k_proto2 proto LDS stride
#define FS    136                           // k_proto2 feat LDS stride

#if __has_builtin(__builtin_amdgcn_exp2f)
#define EXP2(x) __builtin_amdgcn_exp2f(x)
#else
#define EXP2(x) __expf((x) * 0.6931471805599453f)
#endif

typedef __attribute__((ext_vector_type(8))) short  short8;   // 8 bf16 (MFMA A/B frag)
typedef __attribute__((ext_vector_type(4))) float  floatx4;  // MFMA C/D frag

__device__ __forceinline__ float bf2f(unsigned short u) {
    union { unsigned int i; float f; } v; v.i = ((unsigned int)u) << 16; return v.f;
}
__device__ __forceinline__ unsigned short f2bf(float x) {   // RNE
    union { float f; unsigned int i; } v; v.f = x;
    return (unsigned short)((v.i + 0x7fffu + ((v.i >> 16) & 1u)) >> 16);
}
__device__ __forceinline__ float lo_bf(unsigned int u) {
    union { unsigned int i; float f; } v; v.i = u << 16; return v.f;
}
__device__ __forceinline__ float hi_bf(unsigned int u) {
    union { unsigned int i; float f; } v; v.i = u & 0xffff0000u; return v.f;
}

// ---------------------------------------------------------------- k_proto2
// 512 blocks x 256 thr; 16 feature rows per block. Emits Psum/expPsum/PLab/nf,
// Fb = bf16(f), Fz = novel? bf16(C*f):0, gpart[block] = block colsum(Fz),
// nfcnt[block] = block novel count. Block 0 zeroes out[0].
__global__ __launch_bounds__(256) void k_proto2(
        const float* __restrict__ feat, const int* __restrict__ labels,
        const float* __restrict__ protos, const int* __restrict__ plabels,
        float* __restrict__ Psum, float* __restrict__ expPsum,
        float* __restrict__ PLab, int* __restrict__ nf,
        int* __restrict__ nfcnt,
        unsigned short* __restrict__ Fb, unsigned short* __restrict__ Fz,
        float* __restrict__ gpart, float* __restrict__ out) {
    __shared__ unsigned short protoB[128 * PS];
    __shared__ unsigned short featB[16 * FS];
    __shared__ float zcol[16][128];
    __shared__ int labL[16];
    __shared__ int plabL[B_PRO];
    __shared__ int novL[16];

    const int tid = threadIdx.x;
    const int rowBase = blockIdx.x * 16;

    if (blockIdx.x == 0 && tid == 0) out[0] = 0.f;   // k_final accumulates later

    if (tid < B_PRO) plabL[tid] = plabels[tid];
    if (tid >= 128 && tid < 144) labL[tid - 128] = labels[rowBase + tid - 128];

    // stage protos -> bf16 LDS (rows >= 100 zeroed). thread: row tid>>1, half tid&1.
    {
        const int pr = tid >> 1, h = tid & 1;
        unsigned short* dst = &protoB[pr * PS + h * 64];
        if (pr < B_PRO) {
            const float* src = protos + pr * K_DIM + h * 64;
            #pragma unroll
            for (int j = 0; j < 16; ++j) {
                float4 v = ((const float4*)src)[j];
                *(ushort4*)&dst[j * 4] = make_ushort4(f2bf(v.x), f2bf(v.y), f2bf(v.z), f2bf(v.w));
            }
        } else {
            #pragma unroll
            for (int j = 0; j < 16; ++j) *(ushort4*)&dst[j * 4] = make_ushort4(0, 0, 0, 0);
        }
    }

    // stage this thread's feat segment (row rp, cols pq*8..+7) -> LDS + Fb.
    const int rp = tid >> 4, pq = tid & 15;
    float4 fa, fb4;
    {
        const float* src = feat + (size_t)(rowBase + rp) * K_DIM + pq * 8;
        fa  = ((const float4*)src)[0];
        fb4 = ((const float4*)src)[1];
        ushort4 o0 = make_ushort4(f2bf(fa.x), f2bf(fa.y), f2bf(fa.z), f2bf(fa.w));
        ushort4 o1 = make_ushort4(f2bf(fb4.x), f2bf(fb4.y), f2bf(fb4.z), f2bf(fb4.w));
        *(ushort4*)&featB[rp * FS + pq * 8]     = o0;
        *(ushort4*)&featB[rp * FS + pq * 8 + 4] = o1;
        unsigned short* fbd = Fb + (size_t)(rowBase + rp) * K_DIM + pq * 8;
        *(ushort4*)&fbd[0] = o0;
        *(ushort4*)&fbd[4] = o1;
    }
    __syncthreads();

    float acc[8];
    #pragma unroll
    for (int s = 0; s < 8; ++s) acc[s] = 0.f;

    const unsigned short* fRow = &featB[rp * FS];
    for (int kc = 0; kc < K_DIM; kc += 16) {
        uint4 q0 = *(const uint4*)&fRow[kc];
        uint4 q1 = *(const uint4*)&fRow[kc + 8];
        float f[16];
        f[0]=lo_bf(q0.x); f[1]=hi_bf(q0.x); f[2]=lo_bf(q0.y); f[3]=hi_bf(q0.y);
        f[4]=lo_bf(q0.z); f[5]=hi_bf(q0.z); f[6]=lo_bf(q0.w); f[7]=hi_bf(q0.w);
        f[8]=lo_bf(q1.x); f[9]=hi_bf(q1.x); f[10]=lo_bf(q1.y); f[11]=hi_bf(q1.y);
        f[12]=lo_bf(q1.z); f[13]=hi_bf(q1.z); f[14]=lo_bf(q1.w); f[15]=hi_bf(q1.w);
        #pragma unroll
        for (int s = 0; s < 8; ++s) {
            const int b = pq + (s & 3) * 16 + (s >> 2) * 64;
            const unsigned short* pRow = &protoB[b * PS];
            uint4 p0 = *(const uint4*)&pRow[kc];
            uint4 p1 = *(const uint4*)&pRow[kc + 8];
            float a = acc[s];
            a += lo_bf(p0.x)*f[0];  a += hi_bf(p0.x)*f[1];
            a += lo_bf(p0.y)*f[2];  a += hi_bf(p0.y)*f[3];
            a += lo_bf(p0.z)*f[4];  a += hi_bf(p0.z)*f[5];
            a += lo_bf(p0.w)*f[6];  a += hi_bf(p0.w)*f[7];
            a += lo_bf(p1.x)*f[8];  a += hi_bf(p1.x)*f[9];
            a += lo_bf(p1.y)*f[10]; a += hi_bf(p1.y)*f[11];
            a += lo_bf(p1.z)*f[12]; a += hi_bf(p1.z)*f[13];
            a += lo_bf(p1.w)*f[14]; a += hi_bf(p1.w)*f[15];
            acc[s] = a;
        }
    }

    // per-row epilogue: mask b<100, reduce over the 16 pq lanes
    const int lbl = labL[rp];
    float psum = 0.f, esum = 0.f, plab = 0.f, flg = 0.f;
    #pragma unroll
    for (int s = 0; s < 8; ++s) {
        const int b = pq + (s & 3) * 16 + (s >> 2) * 64;
        if (b < B_PRO) {
            const float Pv = acc[s] * INV_T;
            psum += Pv;
            esum += __expf(Pv);
            if (b == lbl) plab += Pv;
            if (plabL[b] == lbl) flg = 1.f;
        }
    }
    for (int off = 1; off < 16; off <<= 1) {
        psum += __shfl_xor(psum, off);
        esum += __shfl_xor(esum, off);
        plab += __shfl_xor(plab, off);
        flg  += __shfl_xor(flg,  off);
    }

    // Fz write + zcol (exact bf16 values into LDS for the column sum)
    {
        const bool nov = (flg == 0.f);
        ushort4 z0 = make_ushort4(0,0,0,0), z1 = z0;
        if (nov) {
            z0 = make_ushort4(f2bf(fa.x*C_SCALE), f2bf(fa.y*C_SCALE),
                              f2bf(fa.z*C_SCALE), f2bf(fa.w*C_SCALE));
            z1 = make_ushort4(f2bf(fb4.x*C_SCALE), f2bf(fb4.y*C_SCALE),
                              f2bf(fb4.z*C_SCALE), f2bf(fb4.w*C_SCALE));
        }
        unsigned short* fzd = Fz + (size_t)(rowBase + rp) * K_DIM + pq * 8;
        *(ushort4*)&fzd[0] = z0;
        *(ushort4*)&fzd[4] = z1;
        float* zc = &zcol[rp][pq * 8];
        zc[0] = bf2f(z0.x); zc[1] = bf2f(z0.y); zc[2] = bf2f(z0.z); zc[3] = bf2f(z0.w);
        zc[4] = bf2f(z1.x); zc[5] = bf2f(z1.y); zc[6] = bf2f(z1.z); zc[7] = bf2f(z1.w);
    }

    if (pq == 0) {
        const int i = rowBase + rp;
        Psum[i] = psum; expPsum[i] = esum; PLab[i] = plab;
        const int nov = (flg > 0.f) ? 0 : 1;
        nf[i] = nov;
        novL[rp] = nov;
    }

    __syncthreads();
    if (tid < 128) {
        float s = 0.f;
        #pragma unroll
        for (int r = 0; r < 16; ++r) s += zcol[r][tid];
        gpart[blockIdx.x * 128 + tid] = s;         // non-atomic partial
    } else if (tid == 255) {
        int c = 0;
        #pragma unroll
        for (int r = 0; r < 16; ++r) c += novL[r];
        nfcnt[blockIdx.x] = c;                     // non-atomic partial
    }
}

// ---------------------------------------------------------------- k_main
// Round-6 body (measured best): 64 rows x CJ cols, a_frag register-resident,
// B streamed from L2 with 1-deep register prefetch, no LDS tiles/barriers in
// the loop. NEW TAIL: blocks with y==0 also reduce gpart -> g (16-col slice
// per x) and nfcnt -> Nn (x==0) — done once, hidden under the other blocks.
__global__ __launch_bounds__(256, 2) void k_main(const unsigned short* __restrict__ Fb,
                                                 const unsigned short* __restrict__ Fz,
                                                 float* __restrict__ rowSumPart,
                                                 const float* __restrict__ gpart,
                                                 const int* __restrict__ nfcnt,
                                                 float* __restrict__ gOut,
                                                 int* __restrict__ NnOut) {
    __shared__ float Re[4][64];
    __shared__ float gred[16][16];

    const int rowBase = blockIdx.y * 64;
    const int tid = threadIdx.x;
    const int wave = tid >> 6, lane = tid & 63;
    const int quad = lane >> 4, c = lane & 15;

    // A fragments straight from global: rows mt*16+c, k = ks*32+quad*8..+7
    short8 a_frag[4][4];
    #pragma unroll
    for (int mt = 0; mt < 4; ++mt)
        #pragma unroll
        for (int ks = 0; ks < 4; ++ks)
            a_frag[mt][ks] = *(const short8*)(Fb + (size_t)(rowBase + mt * 16 + c) * K_DIM
                                              + ks * 32 + quad * 8);

    float accE[4][4];
    #pragma unroll
    for (int mt = 0; mt < 4; ++mt)
        #pragma unroll
        for (int r = 0; r < 4; ++r) accE[mt][r] = 0.f;

    // this lane's column for step s: colBase + s*64 + wave*16 + c
    const unsigned short* bptr = Fz + (size_t)(blockIdx.x * CJ + wave * 16 + c) * K_DIM
                                 + quad * 8;
    short8 c0 = *(const short8*)(bptr);
    short8 c1 = *(const short8*)(bptr + 32);
    short8 c2 = *(const short8*)(bptr + 64);
    short8 c3 = *(const short8*)(bptr + 96);

    const int NSTEP = CJ / 64;
    #pragma unroll 1
    for (int s = 0; s < NSTEP; ++s) {
        // prefetch next step's fragments (last iter: reload same addr — in
        // bounds, result unused)
        const unsigned short* np = bptr + ((s + 1 < NSTEP) ? (size_t)(64 * K_DIM) : 0);
        short8 n0 = *(const short8*)(np);
        short8 n1 = *(const short8*)(np + 32);
        short8 n2 = *(const short8*)(np + 64);
        short8 n3 = *(const short8*)(np + 96);
        bptr = np;

        floatx4 D[4];
        #pragma unroll
        for (int mt = 0; mt < 4; ++mt) D[mt] = (floatx4){0.f, 0.f, 0.f, 0.f};
        #pragma unroll
        for (int mt = 0; mt < 4; ++mt) {
            D[mt] = __builtin_amdgcn_mfma_f32_16x16x32_bf16(a_frag[mt][0], c0, D[mt], 0, 0, 0);
            D[mt] = __builtin_amdgcn_mfma_f32_16x16x32_bf16(a_frag[mt][1], c1, D[mt], 0, 0, 0);
            D[mt] = __builtin_amdgcn_mfma_f32_16x16x32_bf16(a_frag[mt][2], c2, D[mt], 0, 0, 0);
            D[mt] = __builtin_amdgcn_mfma_f32_16x16x32_bf16(a_frag[mt][3], c3, D[mt], 0, 0, 0);
        }
        #pragma unroll
        for (int mt = 0; mt < 4; ++mt)
            #pragma unroll
            for (int r = 0; r < 4; ++r)
                accE[mt][r] += EXP2(D[mt][r]);   // base cols: exp2(0)=1, removed later

        c0 = n0; c1 = n1; c2 = n2; c3 = n3;
    }

    // reduce over the 16-lane column group
    #pragma unroll
    for (int mt = 0; mt < 4; ++mt)
        #pragma unroll
        for (int r = 0; r < 4; ++r) {
            float e = accE[mt][r];
            for (int off = 1; off < 16; off <<= 1) e += __shfl_xor(e, off);
            if (c == 0) Re[wave][mt * 16 + quad * 4 + r] = e;
        }
    __syncthreads();
    if (tid < 64) {
        const float e = Re[0][tid] + Re[1][tid] + Re[2][tid] + Re[3][tid];
        rowSumPart[(size_t)blockIdx.x * M_TOT + rowBase + tid] = e;   // block-unique
    }

    // -------- one-time g / Nn reduction, spread over the 8 y==0 blocks ----
    if (blockIdx.y == 0) {
        // g slice: cols 16*blockIdx.x .. +15. thread (rseg=tid>>4, cl=tid&15)
        const int cl = (tid & 15) + 16 * blockIdx.x;
        const int rseg = tid >> 4;
        float s = 0.f;
        #pragma unroll 4
        for (int r = rseg; r < 512; r += 16) s += gpart[r * 128 + cl];
        gred[tid >> 4][tid & 15] = s;
        __syncthreads();
        if (tid < 16) {
            float t = 0.f;
            #pragma unroll
            for (int k = 0; k < 16; ++k) t += gred[k][tid];
            gOut[16 * blockIdx.x + tid] = t;
        }
        if (blockIdx.x == 0 && tid >= 64 && tid < 128) {
            const int l = tid - 64;
            int cs = 0;
            #pragma unroll
            for (int r = 0; r < 8; ++r) cs += nfcnt[l + 64 * r];
            for (int off = 1; off < 64; off <<= 1) cs += __shfl_xor(cs, off);
            if (l == 0) *NnOut = cs;
        }
    }
}

// ---------------------------------------------------------------- k_final
// 512 blocks x 256 thr, 16 rows/block. Preamble: load precomputed g[128] and
// Nn (reduced once in k_main). Per row i: sZ = dot(Fb_i, g), dd =
// dot(Fb_i,Fz_i) = D_ii; sumE = sum over the NCHUNK rowSumPart partials.
__global__ __launch_bounds__(256) void k_final(
        const int* __restrict__ nf,
        const float* __restrict__ rowSumPart,
        const float* __restrict__ Psum, const float* __restrict__ expPsum,
        const float* __restrict__ PLab,
        const unsigned short* __restrict__ Fb, const unsigned short* __restrict__ Fz,
        const float* __restrict__ gsrc, const int* __restrict__ NnPtr,
        float* __restrict__ out) {
    __shared__ float g[128];
    __shared__ float sh[16];
    __shared__ int shNn;
    const int tid = threadIdx.x;

    if (tid < 128) g[tid] = gsrc[tid];
    if (tid == 128) shNn = *NnPtr;
    __syncthreads();

    const int rp = tid >> 4, u = tid & 15;
    const int i = blockIdx.x * 16 + rp;
    uint4 qb = ((const uint4*)Fb)[(size_t)i * 16 + u];
    uint4 qz = ((const uint4*)Fz)[(size_t)i * 16 + u];
    float sZ = 0.f, dd = 0.f;
    {
        const float* gv = &g[u * 8];
        float fb[8], fz[8];
        fb[0]=lo_bf(qb.x); fb[1]=hi_bf(qb.x); fb[2]=lo_bf(qb.y); fb[3]=hi_bf(qb.y);
        fb[4]=lo_bf(qb.z); fb[5]=hi_bf(qb.z); fb[6]=lo_bf(qb.w); fb[7]=hi_bf(qb.w);
        fz[0]=lo_bf(qz.x); fz[1]=hi_bf(qz.x); fz[2]=lo_bf(qz.y); fz[3]=hi_bf(qz.y);
        fz[4]=lo_bf(qz.z); fz[5]=hi_bf(qz.z); fz[6]=lo_bf(qz.w); fz[7]=hi_bf(qz.w);
        #pragma unroll
        for (int e = 0; e < 8; ++e) { sZ += fb[e] * gv[e]; dd += fb[e] * fz[e]; }
    }
    // rowSumExp partials: lanes u < NCHUNK each grab one chunk's partial
    float ep = (u < NCHUNK) ? rowSumPart[(size_t)u * M_TOT + i] : 0.f;
    for (int off = 1; off < 16; off <<= 1) {
        sZ += __shfl_xor(sZ, off);
        dd += __shfl_xor(dd, off);
        ep += __shfl_xor(ep, off);
    }

    if (u == 0) {
        const int Nn = shNn;
        const float nzero = (float)(M_TOT - Nn);
        const float sumEadj = ep - nzero;             // remove base-column exp2(0)=1 terms
        float contrib;
        if (nf[i]) {
            const float cnt = (float)(Nn - 1);
            const float sumE = sumEadj - EXP2(dd);            // remove own diagonal
            const float denom = sumE + Psum[i];               // + RAW proto logit sum (faithful)
            const float sumS_raw = (sZ - dd) * INV_C;         // sum_{j novel, j!=i} dot_ij
            const float num = INV_T * sumS_raw - logf(denom) * cnt;
            const float sc = cnt > 0.f ? cnt : 1.f;
            contrib = -(num / sc);
        } else {
            contrib = -(PLab[i] - logf(sumEadj + expPsum[i]));
        }
        sh[rp] = contrib;
    }
    __syncthreads();
    if (tid == 0) {
        float s = 0.f;
        #pragma unroll
        for (int r = 0; r < 16; ++r) s += sh[r];
        atomicAdd(out, s * (1.0f / (float)M_TOT));
    }
}

// ---------------------------------------------------------------- launch
extern "C" void kernel_launch(void* const* d_in, const int* in_sizes, int n_in,
                              void* d_out, int out_size, void* d_ws, size_t ws_size,
                              hipStream_t stream) {
    const float* feat    = (const float*)d_in[0];
    const int*   labels  = (const int*)d_in[1];
    const float* protos  = (const float*)d_in[2];
    const int*   plabels = (const int*)d_in[3];
    float* out = (float*)d_out;

    char* ws = (char*)d_ws;
    int*   nfcnt      = (int*)ws;                    // 512 ints
    int*   NnOut      = (int*)(ws + 4096);
    float* gOut       = (float*)(ws + 4608);         // 128 floats
    float* gpart      = (float*)(ws + 8192);         // 512 x 128 fp32 (256 KB)
    float* rowSumPart = (float*)(ws + 270336);       // NCHUNK x 8192 fp32 (256 KB)
    float* Psum       = (float*)(ws + 532480);
    float* expPsum    = (float*)(ws + 565248);
    float* PLab       = (float*)(ws + 598016);
    int*   nf         = (int*)(ws + 630784);
    unsigned short* Fb = (unsigned short*)(ws + 663552);            // 2 MB, 16B aligned
    unsigned short* Fz = (unsigned short*)(ws + 663552 + 2097152);  // 2 MB, 16B aligned

    k_proto2<<<M_TOT / 16, 256, 0, stream>>>(feat, labels, protos, plabels,
                                             Psum, expPsum, PLab, nf, nfcnt,
                                             Fb, Fz, gpart, out);
    dim3 gmain(NCHUNK, M_TOT / 64);   // 8 x 128
    k_main<<<gmain, 256, 0, stream>>>(Fb, Fz, rowSumPart, gpart, nfcnt, gOut, NnOut);
    k_final<<<M_TOT / 16, 256, 0, stream>>>(nf, rowSumPart, Psum, expPsum, PLab,
                                            Fb, Fz, gOut, NnOut, out);
}